// Round 4
// baseline (409.386 us; speedup 1.0000x reference)
//
#include <hip/hip_runtime.h>

#define VB 0.22360679774997896f  // 20^-0.5

typedef __attribute__((ext_vector_type(8))) _Float16 half8;
typedef __attribute__((ext_vector_type(4))) float f32x4;

// ---------------------------------------------------------------------------
// Stage 1 (fp16 MFMA): 512 blocks = 2 batch-halves x 256 patches, 256 thr.
// Block map: p=(bid&7)*32+((bid>>3)&31), h=bid>>8 -> batch-halves and the 4
// jblk-siblings of a patch land on the same XCD (L2 shares W and x lines).
// Per site: GEMM feat[64x96] @ W[96x400] via mfma_f32_16x16x32_f16 in 5
// u-chunks of 80 cols; W reg-staged one chunk ahead; chain matvec fused.
// BN: raw y to z1 + global atomic sums (gs1, gq1), consumed by stage 2.
// ---------------------------------------------------------------------------
__global__ __launch_bounds__(256, 2)
void stage1_kernel(const float* __restrict__ x,
                   const float* __restrict__ cores1,
                   const float* __restrict__ label1,
                   float* __restrict__ z1,
                   float* __restrict__ gs1,
                   float* __restrict__ gq1)
{
    __shared__ __align__(16) float MchunkS[64 * 81];     // 20736 B (aliases xS[64*49])
    __shared__ __align__(16) _Float16 featFragS[6144];   // 12288 B
    __shared__ __align__(16) _Float16 wfragS[7680];      // 15360 B
    __shared__ __align__(16) float leftS[64 * 20];       // 5120 B
    float* xS = MchunkS;

    const int tid = threadIdx.x;
    const int bid = blockIdx.x;
    const int p   = (bid & 7) * 32 + ((bid >> 3) & 31);
    const int h   = bid >> 8;
    const int b0  = h * 64;

    const int hh  = (p >> 7) * 16 + ((p >> 2) & 15);
    const int ww0 = ((p >> 6) & 1) * 16 + (p & 3) * 4;

    // ---- x preload: the 4 sites are 4 consecutive floats -> one float4 ----
    float4 xreg[12];
    #pragma unroll
    for (int k = 0; k < 12; ++k) {
        int idx = tid + k * 256;               // 0..3071 = 64 b x 48 c
        int bb = idx / 48, c = idx - bb * 48;
        xreg[k] = *(const float4*)(x + (((size_t)((b0 + bb) * 48 + c)) << 10)
                                     + hh * 32 + ww0);
    }

    const float* wsite = cores1 + (size_t)p * 153600;  // 4 sites * 38400

    // ---- W reg-prefetch buffers (chunk = 1920 float4) ----
    float4 wrA[8], wrB[8];
    #pragma unroll
    for (int k = 0; k < 8; ++k) {
        int i4 = tid + k * 256;
        if (i4 < 1920) wrA[k] = *(const float4*)(wsite + i4 * 4);
    }

    for (int i = tid; i < 1280; i += 256) leftS[i] = VB;

    float lacc[5];

    #pragma unroll
    for (int n = 0; n < 4; ++n) {
        // ---- site head ----
        if (n > 0) {
            __syncthreads();   // all chain reads of leftS/Mchunk done
            const int bb = tid >> 2, mh = tid & 3;
            #pragma unroll
            for (int j = 0; j < 5; ++j) leftS[bb * 20 + mh * 5 + j] = lacc[j];
        }
        #pragma unroll
        for (int j = 0; j < 5; ++j) lacc[j] = 0.f;
        __syncthreads();       // leftS visible; xS (Mchunk) free
        #pragma unroll
        for (int k = 0; k < 12; ++k) {
            int idx = tid + k * 256;
            int bb = idx / 48, c = idx - bb * 48;
            float v = (n == 0) ? xreg[k].x : (n == 1) ? xreg[k].y
                    : (n == 2) ? xreg[k].z : xreg[k].w;
            xS[bb * 49 + c] = v;
        }
        __syncthreads();       // xS ready
        // featFrag: [(mt*3+ks)*64+l]*8+j ; k-in-K32 = (l>>4)*8+j
        #pragma unroll
        for (int kk = 0; kk < 3; ++kk) {
            int g = tid + kk * 256;            // < 768
            int mtks = g >> 6, l = g & 63;
            int mt = mtks / 3, ks = mtks - mt * 3;
            int row = mt * 16 + (l & 15);
            int f0  = ks * 32 + ((l >> 4) << 3);
            half8 hv;
            if (f0 < 48) {
                #pragma unroll
                for (int j = 0; j < 8; ++j) hv[j] = (_Float16)xS[row * 49 + f0 + j];
            } else {
                #pragma unroll
                for (int j = 0; j < 8; ++j) hv[j] = (_Float16)(1.f - xS[row * 49 + f0 - 48 + j]);
            }
            *(half8*)&featFragS[g * 8] = hv;
        }

        #pragma unroll 1
        for (int uc = 0; uc < 5; ++uc) {
            const int pb = n * 5 + uc;
            // ---- W frag-build from regs; prefetch chunk pb+1 ----
            const float4* wr = (pb & 1) ? wrB : wrA;
            #pragma unroll
            for (int k = 0; k < 8; ++k) {
                int i4 = tid + k * 256;
                if (i4 < 1920) {
                    float vals[4] = {wr[k].x, wr[k].y, wr[k].z, wr[k].w};
                    #pragma unroll
                    for (int t = 0; t < 4; ++t) {
                        int e = i4 * 4 + t;            // [ul][f][v], v inner
                        int v = e % 20;
                        int r = e / 20;
                        int f = r % 96;
                        int ul = r / 96;
                        int c = ul * 20 + v;           // 0..79 col
                        int addr = (((f >> 5) * 5 + (c >> 4)) * 64 +
                                    ((f >> 3) & 3) * 16 + (c & 15)) * 8 + (f & 7);
                        wfragS[addr] = (_Float16)vals[t];
                    }
                }
            }
            if (pb < 19) {
                const float* wb2 = wsite + (size_t)(pb + 1) * 7680;
                float4* wrN = (pb & 1) ? wrA : wrB;
                #pragma unroll
                for (int k = 0; k < 8; ++k) {
                    int i4 = tid + k * 256;
                    if (i4 < 1920) wrN[k] = *(const float4*)(wb2 + i4 * 4);
                }
            }
            __syncthreads();   // wfrag (and featFrag/xS phase) ready

            // ---- MFMA: wave wv owns M-tile wv (16 rows), 5 N-tiles ----
            {
                const int wv = tid >> 6, lane = tid & 63;
                f32x4 acc[5];
                #pragma unroll
                for (int nt = 0; nt < 5; ++nt) acc[nt] = (f32x4){0.f, 0.f, 0.f, 0.f};
                #pragma unroll
                for (int ks = 0; ks < 3; ++ks) {
                    half8 af = *(const half8*)&featFragS[((wv * 3 + ks) * 64 + lane) * 8];
                    #pragma unroll
                    for (int nt = 0; nt < 5; ++nt) {
                        half8 bf = *(const half8*)&wfragS[((ks * 5 + nt) * 64 + lane) * 8];
                        acc[nt] = __builtin_amdgcn_mfma_f32_16x16x32_f16(af, bf, acc[nt], 0, 0, 0);
                    }
                }
                // D: col = lane&15, row = (lane>>4)*4 + r  [m89, dtype-indep]
                const int rowg = lane >> 4, colg = lane & 15;
                #pragma unroll
                for (int nt = 0; nt < 5; ++nt) {
                    #pragma unroll
                    for (int r = 0; r < 4; ++r)
                        MchunkS[(wv * 16 + rowg * 4 + r) * 81 + nt * 16 + colg] = acc[nt][r];
                }
            }
            __syncthreads();   // Mchunk ready; wfrag consumed

            // ---- partial chain ----
            {
                const int mb = tid >> 2, mh = tid & 3;
                #pragma unroll
                for (int ul = 0; ul < 4; ++ul) {
                    float lv = leftS[mb * 20 + uc * 4 + ul];
                    #pragma unroll
                    for (int j = 0; j < 5; ++j)
                        lacc[j] += lv * MchunkS[mb * 81 + ul * 20 + mh * 5 + j];
                }
            }
        }
    }

    // ---- epilogue: label contraction + z1 + BN atomic sums ----
    __syncthreads();
    {
        const int mb = tid >> 2, mh = tid & 3;
        #pragma unroll
        for (int j = 0; j < 5; ++j) leftS[mb * 20 + mh * 5 + j] = lacc[j];
    }
    for (int idx = tid; idx < 400; idx += 256) {   // labv into Mchunk
        int u = idx / 20, o = idx - u * 20;
        const float* lb = label1 + (size_t)((p * 20 + u) * 20 + o) * 20;
        float s = 0.f;
        #pragma unroll
        for (int vv = 0; vv < 20; ++vv) s += lb[vv];
        MchunkS[idx] = s * VB;
    }
    __syncthreads();
    {
        const int mb = tid >> 2, mh = tid & 3;
        float yv[5];
        #pragma unroll
        for (int j = 0; j < 5; ++j) yv[j] = 0.f;
        #pragma unroll
        for (int u = 0; u < 20; ++u) {
            float lv = leftS[mb * 20 + u];
            #pragma unroll
            for (int j = 0; j < 5; ++j) yv[j] += lv * MchunkS[u * 20 + mh * 5 + j];
        }
        float s = 0.f, s2 = 0.f;
        #pragma unroll
        for (int j = 0; j < 5; ++j) {
            z1[(size_t)(b0 + mb) * 5120 + p * 20 + mh * 5 + j] = yv[j];
            s += yv[j]; s2 += yv[j] * yv[j];
        }
        #pragma unroll
        for (int off = 32; off > 0; off >>= 1) {
            s  += __shfl_down(s, off);
            s2 += __shfl_down(s2, off);
        }
        if ((tid & 63) == 0) { atomicAdd(&gs1[p], s); atomicAdd(&gq1[p], s2); }
    }
}

// ---------------------------------------------------------------------------
// Stages 2 & 3: unified affine from global sums (verified formula).
// ---------------------------------------------------------------------------
template <int STAGE>
__global__ __launch_bounds__(512, 2)
void stageN_kernel(const float* __restrict__ zin,
                   const float* __restrict__ cores,
                   const float* __restrict__ label,
                   const float* __restrict__ gsin,
                   const float* __restrict__ gqin,
                   const float* __restrict__ gmin,
                   const float* __restrict__ btin,
                   float* __restrict__ zout,
                   float* __restrict__ gsout,
                   float* __restrict__ gqout)
{
    constexpr int PC  = (STAGE == 2) ? 64 : 16;
    constexpr int ZST = (STAGE == 2) ? 5120 : 1280;
    constexpr int OST = PC * 20;

    __shared__ __align__(16) float featS[64 * 40];
    __shared__ __align__(16) float wS[10 * 704];
    __shared__ __align__(16) float mS[64 * 401];
    __shared__ __align__(16) float leftS[64 * 20];

    const int tid = threadIdx.x;
    const int bid = blockIdx.x;
    const int p   = (STAGE == 2) ? (bid & 63) : (bid & 15);
    const int bc  = (STAGE == 2) ? (bid >> 6) : (bid >> 4);
    const int b0  = bc * 64;

    const int tv = tid & 15;
    const int tb = tid >> 4;
    const int mb = tid >> 2;
    const int mh = tid & 3;

    for (int idx = tid; idx < 64 * 20; idx += 512) leftS[idx] = VB;

    #pragma unroll 1
    for (int n = 0; n < 4; ++n) {
        int hh, ww;
        if (STAGE == 2) {
            hh = (p >> 5) * 8 + ((p >> 1) & 7);
            ww = ((p >> 4) & 1) * 8 + (p & 1) * 4 + n;
        } else {
            hh = (p >> 3) * 4 + (p & 3);
            ww = ((p >> 2) & 1) * 4 + n;
        }
        __syncthreads();
        for (int idx = tid; idx < 64 * 20; idx += 512) {
            int bl = idx / 20;
            int d  = idx - bl * 20;
            int src = (STAGE == 2) ? (d * 256 + hh * 16 + ww)
                                   : (d * 64 + hh * 8 + ww);
            int ch = src / 20;
            float mean = gsin[ch] * (1.f / 2560.f);
            float var  = gqin[ch] * (1.f / 2560.f) - mean * mean;
            float rstd = rsqrtf(var + 1e-5f);
            float sc   = gmin[ch] * rstd;
            float sh   = btin[ch] - mean * sc;
            float val = zin[(size_t)(b0 + bl) * ZST + src] * sc + sh;
            featS[bl * 40 + d]      = val;
            featS[bl * 40 + 20 + d] = 1.f - val;
        }
        const float* wpn = cores + (size_t)(p * 4 + n) * 16000;

        float acc0[25], acc1[25];
        #pragma unroll
        for (int j = 0; j < 25; ++j) { acc0[j] = 0.f; acc1[j] = 0.f; }

        #pragma unroll 1
        for (int ft = 0; ft < 4; ++ft) {
            __syncthreads();
            for (int idx = tid; idx < 4000; idx += 512) {
                int fi = idx / 400;
                int c  = idx - fi * 400;
                int u  = c / 20;
                int vv = c - u * 20;
                int tw = c / 25;
                int jj = c - tw * 25;
                wS[fi * 704 + tw * 44 + jj] =
                    wpn[(u * 40 + ft * 10 + fi) * 20 + vv];
            }
            __syncthreads();
            #pragma unroll
            for (int fi = 0; fi < 10; ++fi) {
                const int f = ft * 10 + fi;
                float a0 = featS[tb * 40 + f];
                float a1 = featS[(tb + 32) * 40 + f];
                float wv[25];
                #pragma unroll
                for (int g = 0; g < 6; ++g) {
                    float4 t = *reinterpret_cast<const float4*>(
                        &wS[fi * 704 + tv * 44 + 4 * g]);
                    wv[4*g+0] = t.x; wv[4*g+1] = t.y;
                    wv[4*g+2] = t.z; wv[4*g+3] = t.w;
                }
                wv[24] = wS[fi * 704 + tv * 44 + 24];
                #pragma unroll
                for (int j = 0; j < 25; ++j) {
                    acc0[j] += a0 * wv[j];
                    acc1[j] += a1 * wv[j];
                }
            }
        }
        #pragma unroll
        for (int j = 0; j < 25; ++j) {
            mS[tb * 401 + tv * 25 + j]        = acc0[j];
            mS[(tb + 32) * 401 + tv * 25 + j] = acc1[j];
        }
        __syncthreads();
        float lacc[5];
        if (tid < 256) {
            #pragma unroll
            for (int j = 0; j < 5; ++j) lacc[j] = 0.f;
            #pragma unroll
            for (int u = 0; u < 20; ++u) {
                float lv = leftS[mb * 20 + u];
                #pragma unroll
                for (int j = 0; j < 5; ++j)
                    lacc[j] += lv * mS[mb * 401 + u * 20 + mh * 5 + j];
            }
        }
        __syncthreads();
        if (tid < 256) {
            #pragma unroll
            for (int j = 0; j < 5; ++j) leftS[mb * 20 + mh * 5 + j] = lacc[j];
        }
    }
    __syncthreads();

    for (int idx = tid; idx < 400; idx += 512) {
        int u = idx / 20;
        int o = idx - u * 20;
        const float* lb = label + (size_t)((p * 20 + u) * 20 + o) * 20;
        float s = 0.f;
        #pragma unroll
        for (int vv = 0; vv < 20; ++vv) s += lb[vv];
        wS[idx] = s * VB;
    }
    __syncthreads();
    if (tid < 256) {
        float yv[5];
        #pragma unroll
        for (int j = 0; j < 5; ++j) yv[j] = 0.f;
        #pragma unroll
        for (int u = 0; u < 20; ++u) {
            float lv = leftS[mb * 20 + u];
            #pragma unroll
            for (int j = 0; j < 5; ++j) yv[j] += lv * wS[u * 20 + mh * 5 + j];
        }
        float s = 0.f, s2 = 0.f;
        #pragma unroll
        for (int j = 0; j < 5; ++j) {
            zout[(size_t)(b0 + mb) * OST + p * 20 + mh * 5 + j] = yv[j];
            s += yv[j]; s2 += yv[j] * yv[j];
        }
        #pragma unroll
        for (int off = 32; off > 0; off >>= 1) {
            s  += __shfl_down(s, off);
            s2 += __shfl_down(s2, off);
        }
        if ((tid & 63) == 0) {
            atomicAdd(&gsout[p], s);
            atomicAdd(&gqout[p], s2);
        }
    }
}

// ---------------------------------------------------------------------------
// Final MPS (unchanged)
// ---------------------------------------------------------------------------
__global__ __launch_bounds__(512, 2)
void final_kernel(const float* __restrict__ z3,
                  const float* __restrict__ coresF,
                  const float* __restrict__ labelF,
                  const float* __restrict__ g3,
                  const float* __restrict__ b3,
                  const float* __restrict__ gsum3,
                  const float* __restrict__ gsq3,
                  float* __restrict__ out)
{
    __shared__ float fS[40];
    __shared__ float mS[400];
    __shared__ float leftS[20];
    __shared__ float lvS[200];
    __shared__ float scS[16], shS[16];

    const int b   = blockIdx.x;
    const int tid = threadIdx.x;

    if (tid < 16) {
        float mean = gsum3[tid] * (1.f / 2560.f);
        float var  = gsq3[tid] * (1.f / 2560.f) - mean * mean;
        float rstd = rsqrtf(var + 1e-5f);
        float sc   = g3[tid] * rstd;
        scS[tid] = sc;
        shS[tid] = b3[tid] - mean * sc;
    }
    if (tid < 20) leftS[tid] = VB;
    __syncthreads();

    #pragma unroll 1
    for (int n = 0; n < 16; ++n) {
        if (tid < 20) {
            float raw = z3[(size_t)b * 320 + n * 20 + tid];
            float val = raw * scS[n] + shS[n];
            fS[tid]      = val;
            fS[20 + tid] = 1.f - val;
        }
        __syncthreads();
        if (tid < 400) {
            int u  = tid / 20;
            int vv = tid - u * 20;
            const float* wb = coresF + ((size_t)(n * 20 + u) * 40) * 20 + vv;
            float acc = 0.f;
            #pragma unroll
            for (int f = 0; f < 40; ++f) acc += fS[f] * wb[f * 20];
            mS[tid] = acc;
        }
        __syncthreads();
        float tmp = 0.f;
        if (tid < 20) {
            #pragma unroll
            for (int u = 0; u < 20; ++u) tmp += leftS[u] * mS[u * 20 + tid];
        }
        __syncthreads();
        if (tid < 20) leftS[tid] = tmp;
        __syncthreads();
    }
    if (tid < 200) {
        int u = tid / 10;
        int o = tid - u * 10;
        const float* lb = labelF + (size_t)(u * 10 + o) * 20;
        float s = 0.f;
        #pragma unroll
        for (int vv = 0; vv < 20; ++vv) s += lb[vv];
        lvS[tid] = s * VB;
    }
    __syncthreads();
    if (tid < 10) {
        float s = 0.f;
        #pragma unroll
        for (int u = 0; u < 20; ++u) s += leftS[u] * lvS[u * 10 + tid];
        out[b * 10 + tid] = s;
    }
}

// ---------------------------------------------------------------------------
extern "C" void kernel_launch(void* const* d_in, const int* in_sizes, int n_in,
                              void* d_out, int out_size, void* d_ws, size_t ws_size,
                              hipStream_t stream)
{
    const float* x      = (const float*)d_in[0];
    const float* cores1 = (const float*)d_in[1];
    const float* label1 = (const float*)d_in[2];
    const float* g1     = (const float*)d_in[3];
    const float* b1     = (const float*)d_in[4];
    const float* cores2 = (const float*)d_in[5];
    const float* label2 = (const float*)d_in[6];
    const float* g2     = (const float*)d_in[7];
    const float* b2     = (const float*)d_in[8];
    const float* cores3 = (const float*)d_in[9];
    const float* label3 = (const float*)d_in[10];
    const float* g3     = (const float*)d_in[11];
    const float* b3     = (const float*)d_in[12];
    const float* coresF = (const float*)d_in[13];
    const float* labelF = (const float*)d_in[14];

    float* ws  = (float*)d_ws;
    float* z1  = ws;                 // 128*256*20 = 655360
    float* z2  = ws + 655360;        // 128*64*20  = 163840
    float* z3  = ws + 819200;        // 128*16*20  = 40960
    float* gs1 = ws + 860160;        // 256
    float* gq1 = ws + 860416;        // 256
    float* gs2 = ws + 860672;        // 64
    float* gq2 = ws + 860736;        // 64
    float* gs3 = ws + 860800;        // 16
    float* gq3 = ws + 860816;        // 16

    // zero all BN atomic-sum regions (gs1..gq3 = 672 floats, contiguous)
    hipMemsetAsync(gs1, 0, 672 * sizeof(float), stream);

    stage1_kernel<<<512, 256, 0, stream>>>(x, cores1, label1, z1, gs1, gq1);
    stageN_kernel<2><<<128, 512, 0, stream>>>(z1, cores2, label2,
                                              gs1, gq1, g1, b1,
                                              z2, gs2, gq2);
    stageN_kernel<3><<<32, 512, 0, stream>>>(z2, cores3, label3,
                                             gs2, gq2, g2, b2,
                                             z3, gs3, gq3);
    final_kernel<<<128, 512, 0, stream>>>(z3, coresF, labelF, g3, b3,
                                          gs3, gq3, (float*)d_out);
}

// Round 5
// 278.292 us; speedup vs baseline: 1.4711x; 1.4711x over previous
//
#include <hip/hip_runtime.h>

#define VB 0.22360679774997896f  // 20^-0.5

typedef __attribute__((ext_vector_type(8))) _Float16 half8;
typedef __attribute__((ext_vector_type(4))) float f32x4;

// workspace float offsets
#define Z1_OFF  0
#define Z2_OFF  655360
#define Z3_OFF  819200
#define GS1_OFF 860160
#define GQ1_OFF 860416
#define GS2_OFF 860672
#define GQ2_OFF 860736
#define GS3_OFF 860800
#define GQ3_OFF 860816
#define XT_OFF  860832
#define M_OFF   7152288            // halfs start at ws+M_OFF (byte 28609152, 16-aligned)
#define M1_BYTES 104857600ULL      // 2*5120 slabs * 5120 halfs * 2B

// ---------------------------------------------------------------------------
// x transpose: x[b][c][pix] -> xT[pix][b*48+c].  1024 blocks, 256 thr.
// ---------------------------------------------------------------------------
__global__ __launch_bounds__(256, 4)
void xt_kernel(const float* __restrict__ x, float* __restrict__ xT)
{
    __shared__ float tS[32 * 193];
    const int tid  = threadIdx.x;
    const int pix0 = (blockIdx.x & 31) * 32;
    const int bc0  = (blockIdx.x >> 5) * 192;
    #pragma unroll
    for (int k = 0; k < 6; ++k) {
        int i = tid + k * 256;                 // 0..1535
        int r = i >> 3, q = i & 7;
        float4 v = *(const float4*)(x + (size_t)(bc0 + r) * 1024 + pix0 + q * 4);
        tS[(q * 4 + 0) * 193 + r] = v.x;
        tS[(q * 4 + 1) * 193 + r] = v.y;
        tS[(q * 4 + 2) * 193 + r] = v.z;
        tS[(q * 4 + 3) * 193 + r] = v.w;
    }
    __syncthreads();
    #pragma unroll
    for (int k = 0; k < 6; ++k) {
        int o = tid + k * 256;
        int pp = o / 48, c4 = o - pp * 48;
        float4 v;
        v.x = tS[pp * 193 + c4 * 4 + 0];
        v.y = tS[pp * 193 + c4 * 4 + 1];
        v.z = tS[pp * 193 + c4 * 4 + 2];
        v.w = tS[pp * 193 + c4 * 4 + 3];
        *(float4*)(xT + (size_t)(pix0 + pp) * 6144 + bc0 + c4 * 4) = v;
    }
}

// ---------------------------------------------------------------------------
// Stage-1 GEMM: grid (5120, bh) = (uc*4+n)*256+p blocks, 256 thr.
// One shot per block: feat[64x96] @ Wchunk[96x80] -> M fp16 slab [64][80].
// ---------------------------------------------------------------------------
__global__ __launch_bounds__(256, 4)
void gemm1_kernel(const float* __restrict__ xT,
                  const float* __restrict__ cores1,
                  _Float16* __restrict__ M,
                  int bh0, int mmask)
{
    __shared__ __align__(16) char regn[15360];          // xS / wfrag / mOut
    __shared__ __align__(16) _Float16 featFragS[6144];  // 12288 B
    float*     xS     = (float*)regn;                   // [64*48]
    _Float16*  wfragS = (_Float16*)regn;                // [7680]
    _Float16*  mOutS  = (_Float16*)regn;                // [64*80]

    const int tid = threadIdx.x;
    const int p   = blockIdx.x & 255;
    const int nuc = blockIdx.x >> 8;                    // 0..19
    const int n   = nuc & 3;
    const int uc  = nuc >> 2;
    const int bh  = bh0 + blockIdx.y;
    const int bhm = bh & mmask;

    const int hh = (p >> 7) * 16 + ((p >> 2) & 15);
    const int ww = ((p >> 6) & 1) * 16 + (p & 3) * 4 + n;

    // issue W chunk loads (7680 floats)
    const float* wsl = cores1 + (size_t)p * 153600 + (size_t)n * 38400 + (size_t)uc * 7680;
    float4 wr[8];
    #pragma unroll
    for (int k = 0; k < 8; ++k) {
        int i4 = tid + k * 256;
        if (i4 < 1920) wr[k] = *(const float4*)(wsl + i4 * 4);
    }
    // x slab (3072 floats, contiguous)
    const float* xsl = xT + (size_t)(hh * 32 + ww) * 6144 + bh * 3072;
    float4 xr[3];
    #pragma unroll
    for (int k = 0; k < 3; ++k) xr[k] = *(const float4*)(xsl + (tid + k * 256) * 4);
    #pragma unroll
    for (int k = 0; k < 3; ++k) *(float4*)&xS[(tid + k * 256) * 4] = xr[k];
    __syncthreads();

    // featFrag: [(mt*3+ks)*64+l]*8, k-in-K32 = (l>>4)*8+j
    #pragma unroll
    for (int kk = 0; kk < 3; ++kk) {
        int g = tid + kk * 256;                 // 0..767
        int mtks = g >> 6, l = g & 63;
        int mt = mtks / 3, ks = mtks - mt * 3;
        int b = mt * 16 + (l & 15);
        int f0 = ks * 32 + ((l >> 4) << 3);
        half8 hv;
        if (f0 < 48) {
            #pragma unroll
            for (int j = 0; j < 8; ++j) hv[j] = (_Float16)xS[b * 48 + f0 + j];
        } else {
            #pragma unroll
            for (int j = 0; j < 8; ++j) hv[j] = (_Float16)(1.f - xS[b * 48 + f0 - 48 + j]);
        }
        *(half8*)&featFragS[g * 8] = hv;
    }
    __syncthreads();                            // xS dead -> wfrag region free

    // wfrag from regs: e = (ul*96+f)*20+v ; col c = ul*20+v
    #pragma unroll
    for (int k = 0; k < 8; ++k) {
        int i4 = tid + k * 256;
        if (i4 < 1920) {
            float vals[4] = {wr[k].x, wr[k].y, wr[k].z, wr[k].w};
            #pragma unroll
            for (int t = 0; t < 4; ++t) {
                int e = i4 * 4 + t;
                int v = e % 20;
                int r = e / 20;
                int f = r % 96;
                int ul = r / 96;
                int c = ul * 20 + v;
                int addr = (((f >> 5) * 5 + (c >> 4)) * 64 +
                            ((f >> 3) & 3) * 16 + (c & 15)) * 8 + (f & 7);
                wfragS[addr] = (_Float16)vals[t];
            }
        }
    }
    __syncthreads();

    // MFMA: wave wv owns rows 16wv..16wv+15, 5 N-tiles, K=96 (3 ks)
    const int wv = tid >> 6, lane = tid & 63;
    f32x4 acc[5];
    #pragma unroll
    for (int nt = 0; nt < 5; ++nt) acc[nt] = (f32x4){0.f, 0.f, 0.f, 0.f};
    #pragma unroll
    for (int ks = 0; ks < 3; ++ks) {
        half8 af = *(const half8*)&featFragS[((wv * 3 + ks) * 64 + lane) * 8];
        #pragma unroll
        for (int nt = 0; nt < 5; ++nt) {
            half8 bf = *(const half8*)&wfragS[((ks * 5 + nt) * 64 + lane) * 8];
            acc[nt] = __builtin_amdgcn_mfma_f32_16x16x32_f16(af, bf, acc[nt], 0, 0, 0);
        }
    }
    __syncthreads();                            // wfrag dead -> mOut region free
    const int rowg = lane >> 4, colg = lane & 15;
    #pragma unroll
    for (int nt = 0; nt < 5; ++nt) {
        #pragma unroll
        for (int r = 0; r < 4; ++r)
            mOutS[(wv * 16 + rowg * 4 + r) * 80 + nt * 16 + colg] = (_Float16)acc[nt][r];
    }
    __syncthreads();
    _Float16* dst = M + ((size_t)bhm * 5120 + (size_t)((p * 4 + n) * 5 + uc)) * 5120;
    #pragma unroll
    for (int k = 0; k < 3; ++k) {
        int i = tid + k * 256;
        if (i < 640) ((uint4*)dst)[i] = ((const uint4*)mOutS)[i];
    }
}

// ---------------------------------------------------------------------------
// Stage-2/3 GEMM: feat from z_prev + BN affine.  F=40 (K padded to 64).
// ---------------------------------------------------------------------------
template <int STAGE>
__global__ __launch_bounds__(256, 4)
void gemmN_kernel(const float* __restrict__ zin,
                  const float* __restrict__ cores,
                  const float* __restrict__ gsin, const float* __restrict__ gqin,
                  const float* __restrict__ gam,  const float* __restrict__ bet,
                  _Float16* __restrict__ M,
                  int bh0, int mmask)
{
    constexpr int PC   = (STAGE == 2) ? 64 : 16;
    constexpr int ZROW = (STAGE == 2) ? 5120 : 1280;

    __shared__ __align__(16) char regn[10240];          // zS / wfrag / mOut
    __shared__ __align__(16) _Float16 featFragS[4096];
    float*     zS     = (float*)regn;                   // [64*20]
    _Float16*  wfragS = (_Float16*)regn;                // [5120]
    _Float16*  mOutS  = (_Float16*)regn;                // [64*80]

    const int tid = threadIdx.x;
    const int p   = blockIdx.x & (PC - 1);
    const int nuc = blockIdx.x / PC;
    const int n   = nuc & 3, uc = nuc >> 2;
    const int bh  = bh0 + blockIdx.y;
    const int bhm = bh & mmask;
    const int bg  = bh * 64;

    int hh, ww;
    if (STAGE == 2) { hh = (p >> 5) * 8 + ((p >> 1) & 7); ww = ((p >> 4) & 1) * 8 + (p & 1) * 4 + n; }
    else            { hh = (p >> 3) * 4 + (p & 3);        ww = ((p >> 2) & 1) * 4 + n; }

    // W chunk (3200 floats)
    const float* wsl = cores + (size_t)(p * 4 + n) * 16000 + uc * 3200;
    float4 wr[4];
    #pragma unroll
    for (int k = 0; k < 4; ++k) {
        int i4 = tid + k * 256;
        if (i4 < 800) wr[k] = *(const float4*)(wsl + i4 * 4);
    }
    // z + affine
    float zv[5];
    #pragma unroll
    for (int k = 0; k < 5; ++k) {
        int idx = tid + k * 256;
        int bl = idx / 20, d = idx - bl * 20;
        int src = (STAGE == 2) ? (d * 256 + hh * 16 + ww) : (d * 64 + hh * 8 + ww);
        int ch = src / 20;
        float mean = gsin[ch] * (1.f / 2560.f);
        float var  = gqin[ch] * (1.f / 2560.f) - mean * mean;
        float rstd = rsqrtf(var + 1e-5f);
        float sc = gam[ch] * rstd;
        float sh = bet[ch] - mean * sc;
        zv[k] = zin[(size_t)(bg + bl) * ZROW + src] * sc + sh;
    }
    #pragma unroll
    for (int k = 0; k < 5; ++k) zS[tid + k * 256] = zv[k];
    __syncthreads();

    // featFrag: [(mt*2+ks)*64+l]*8
    #pragma unroll
    for (int kk = 0; kk < 2; ++kk) {
        int g = tid + kk * 256;                 // 0..511
        int mtks = g >> 6, l = g & 63;
        int mt = mtks >> 1, ks = mtks & 1;
        int bl = mt * 16 + (l & 15);
        int f0 = ks * 32 + ((l >> 4) << 3);
        half8 hv;
        #pragma unroll
        for (int j = 0; j < 8; ++j) {
            int f = f0 + j;
            float val = (f < 20) ? zS[bl * 20 + f]
                      : (f < 40) ? (1.f - zS[bl * 20 + f - 20]) : 0.f;
            hv[j] = (_Float16)val;
        }
        *(half8*)&featFragS[g * 8] = hv;
    }
    __syncthreads();                            // zS dead

    // wfrag: zero-init (K padding), then scatter
    #pragma unroll
    for (int k = 0; k < 3; ++k) {
        int i = tid + k * 256;
        if (i < 640) ((uint4*)wfragS)[i] = (uint4){0, 0, 0, 0};
    }
    __syncthreads();
    #pragma unroll
    for (int k = 0; k < 4; ++k) {
        int i4 = tid + k * 256;
        if (i4 < 800) {
            float vals[4] = {wr[k].x, wr[k].y, wr[k].z, wr[k].w};
            #pragma unroll
            for (int t = 0; t < 4; ++t) {
                int e = i4 * 4 + t;
                int v = e % 20;
                int r = e / 20;
                int f = r % 40;
                int ul = r / 40;
                int c = ul * 20 + v;
                int addr = (((f >> 5) * 5 + (c >> 4)) * 64 +
                            ((f >> 3) & 3) * 16 + (c & 15)) * 8 + (f & 7);
                wfragS[addr] = (_Float16)vals[t];
            }
        }
    }
    __syncthreads();

    const int wv = tid >> 6, lane = tid & 63;
    f32x4 acc[5];
    #pragma unroll
    for (int nt = 0; nt < 5; ++nt) acc[nt] = (f32x4){0.f, 0.f, 0.f, 0.f};
    #pragma unroll
    for (int ks = 0; ks < 2; ++ks) {
        half8 af = *(const half8*)&featFragS[((wv * 2 + ks) * 64 + lane) * 8];
        #pragma unroll
        for (int nt = 0; nt < 5; ++nt) {
            half8 bf = *(const half8*)&wfragS[((ks * 5 + nt) * 64 + lane) * 8];
            acc[nt] = __builtin_amdgcn_mfma_f32_16x16x32_f16(af, bf, acc[nt], 0, 0, 0);
        }
    }
    __syncthreads();
    const int rowg = lane >> 4, colg = lane & 15;
    #pragma unroll
    for (int nt = 0; nt < 5; ++nt) {
        #pragma unroll
        for (int r = 0; r < 4; ++r)
            mOutS[(wv * 16 + rowg * 4 + r) * 80 + nt * 16 + colg] = (_Float16)acc[nt][r];
    }
    __syncthreads();
    _Float16* dst = M + ((size_t)bhm * PC * 20 + (size_t)((p * 4 + n) * 5 + uc)) * 5120;
    #pragma unroll
    for (int k = 0; k < 3; ++k) {
        int i = tid + k * 256;
        if (i < 640) ((uint4*)dst)[i] = ((const uint4*)mOutS)[i];
    }
}

// ---------------------------------------------------------------------------
// Chain kernel: per patch p, 64-batch slice: 4-site left-chain over M fp16,
// label contraction, raw y out + BN atomic sums.
// ---------------------------------------------------------------------------
template <int P, int ZROW>
__global__ __launch_bounds__(256, 2)
void chain_kernel(const _Float16* __restrict__ M,
                  const float* __restrict__ label,
                  float* __restrict__ zout,
                  float* __restrict__ gs, float* __restrict__ gq,
                  int b0, int mmask)
{
    __shared__ __align__(16) _Float16 mS[25600];  // 51200 B (labv aliases)
    __shared__ __align__(16) float leftS[64 * 20];
    float* labv = (float*)mS;

    const int tid = threadIdx.x;
    const int p   = blockIdx.x;
    const int bg  = b0 + blockIdx.y * 64;
    const int bhm = (bg >> 6) & mmask;

    for (int i = tid; i < 1280; i += 256) leftS[i] = VB;

    const int mb = tid >> 2, mh = tid & 3;
    #pragma unroll 1
    for (int n = 0; n < 4; ++n) {
        __syncthreads();    // leftS ready; mS free
        const uint4* src = (const uint4*)(M + ((size_t)bhm * P * 20 + (size_t)(p * 4 + n) * 5) * 5120);
        for (int i = tid; i < 3200; i += 256) ((uint4*)mS)[i] = src[i];
        __syncthreads();
        float lacc[5] = {0.f, 0.f, 0.f, 0.f, 0.f};
        #pragma unroll
        for (int u = 0; u < 20; ++u) {
            int uci = u >> 2, ul = u & 3;
            float lv = leftS[mb * 20 + u];
            #pragma unroll
            for (int j = 0; j < 5; ++j)
                lacc[j] += lv * (float)mS[uci * 5120 + mb * 80 + ul * 20 + mh * 5 + j];
        }
        __syncthreads();
        #pragma unroll
        for (int j = 0; j < 5; ++j) leftS[mb * 20 + mh * 5 + j] = lacc[j];
    }
    __syncthreads();
    for (int idx = tid; idx < 400; idx += 256) {
        int u = idx / 20, o = idx - u * 20;
        const float* lb = label + (size_t)((p * 20 + u) * 20 + o) * 20;
        float s = 0.f;
        #pragma unroll
        for (int vv = 0; vv < 20; ++vv) s += lb[vv];
        labv[idx] = s * VB;
    }
    __syncthreads();
    float yv[5];
    #pragma unroll
    for (int j = 0; j < 5; ++j) yv[j] = 0.f;
    #pragma unroll
    for (int u = 0; u < 20; ++u) {
        float lv = leftS[mb * 20 + u];
        #pragma unroll
        for (int j = 0; j < 5; ++j) yv[j] += lv * labv[u * 20 + mh * 5 + j];
    }
    float s = 0.f, s2 = 0.f;
    #pragma unroll
    for (int j = 0; j < 5; ++j) {
        zout[(size_t)(bg + mb) * ZROW + p * 20 + mh * 5 + j] = yv[j];
        s += yv[j]; s2 += yv[j] * yv[j];
    }
    #pragma unroll
    for (int off = 32; off > 0; off >>= 1) {
        s  += __shfl_down(s, off);
        s2 += __shfl_down(s2, off);
    }
    if ((tid & 63) == 0) { atomicAdd(&gs[p], s); atomicAdd(&gq[p], s2); }
}

// ---------------------------------------------------------------------------
// Final MPS (unchanged, verified)
// ---------------------------------------------------------------------------
__global__ __launch_bounds__(512, 2)
void final_kernel(const float* __restrict__ z3,
                  const float* __restrict__ coresF,
                  const float* __restrict__ labelF,
                  const float* __restrict__ g3,
                  const float* __restrict__ b3,
                  const float* __restrict__ gsum3,
                  const float* __restrict__ gsq3,
                  float* __restrict__ out)
{
    __shared__ float fS[40];
    __shared__ float mS[400];
    __shared__ float leftS[20];
    __shared__ float lvS[200];
    __shared__ float scS[16], shS[16];

    const int b   = blockIdx.x;
    const int tid = threadIdx.x;

    if (tid < 16) {
        float mean = gsum3[tid] * (1.f / 2560.f);
        float var  = gsq3[tid] * (1.f / 2560.f) - mean * mean;
        float rstd = rsqrtf(var + 1e-5f);
        float sc   = g3[tid] * rstd;
        scS[tid] = sc;
        shS[tid] = b3[tid] - mean * sc;
    }
    if (tid < 20) leftS[tid] = VB;
    __syncthreads();

    #pragma unroll 1
    for (int n = 0; n < 16; ++n) {
        if (tid < 20) {
            float raw = z3[(size_t)b * 320 + n * 20 + tid];
            float val = raw * scS[n] + shS[n];
            fS[tid]      = val;
            fS[20 + tid] = 1.f - val;
        }
        __syncthreads();
        if (tid < 400) {
            int u  = tid / 20;
            int vv = tid - u * 20;
            const float* wb = coresF + ((size_t)(n * 20 + u) * 40) * 20 + vv;
            float acc = 0.f;
            #pragma unroll
            for (int f = 0; f < 40; ++f) acc += fS[f] * wb[f * 20];
            mS[tid] = acc;
        }
        __syncthreads();
        float tmp = 0.f;
        if (tid < 20) {
            #pragma unroll
            for (int u = 0; u < 20; ++u) tmp += leftS[u] * mS[u * 20 + tid];
        }
        __syncthreads();
        if (tid < 20) leftS[tid] = tmp;
        __syncthreads();
    }
    if (tid < 200) {
        int u = tid / 10;
        int o = tid - u * 10;
        const float* lb = labelF + (size_t)(u * 10 + o) * 20;
        float s = 0.f;
        #pragma unroll
        for (int vv = 0; vv < 20; ++vv) s += lb[vv];
        lvS[tid] = s * VB;
    }
    __syncthreads();
    if (tid < 10) {
        float s = 0.f;
        #pragma unroll
        for (int u = 0; u < 20; ++u) s += leftS[u] * lvS[u * 10 + tid];
        out[b * 10 + tid] = s;
    }
}

// ---------------------------------------------------------------------------
extern "C" void kernel_launch(void* const* d_in, const int* in_sizes, int n_in,
                              void* d_out, int out_size, void* d_ws, size_t ws_size,
                              hipStream_t stream)
{
    const float* x      = (const float*)d_in[0];
    const float* cores1 = (const float*)d_in[1];
    const float* label1 = (const float*)d_in[2];
    const float* g1     = (const float*)d_in[3];
    const float* b1     = (const float*)d_in[4];
    const float* cores2 = (const float*)d_in[5];
    const float* label2 = (const float*)d_in[6];
    const float* g2     = (const float*)d_in[7];
    const float* b2     = (const float*)d_in[8];
    const float* cores3 = (const float*)d_in[9];
    const float* label3 = (const float*)d_in[10];
    const float* g3     = (const float*)d_in[11];
    const float* b3     = (const float*)d_in[12];
    const float* coresF = (const float*)d_in[13];
    const float* labelF = (const float*)d_in[14];

    float* ws  = (float*)d_ws;
    float* z1  = ws + Z1_OFF;
    float* z2  = ws + Z2_OFF;
    float* z3  = ws + Z3_OFF;
    float* gs1 = ws + GS1_OFF; float* gq1 = ws + GQ1_OFF;
    float* gs2 = ws + GS2_OFF; float* gq2 = ws + GQ2_OFF;
    float* gs3 = ws + GS3_OFF; float* gq3 = ws + GQ3_OFF;
    float* xT  = ws + XT_OFF;
    _Float16* M = (_Float16*)(ws + M_OFF);

    hipMemsetAsync(gs1, 0, 672 * sizeof(float), stream);
    xt_kernel<<<1024, 256, 0, stream>>>(x, xT);

    const bool full = ws_size >= (size_t)M_OFF * 4 + M1_BYTES;
    if (full) {
        gemm1_kernel<<<dim3(5120, 2), 256, 0, stream>>>(xT, cores1, M, 0, 1);
        chain_kernel<256, 5120><<<dim3(256, 2), 256, 0, stream>>>(M, label1, z1, gs1, gq1, 0, 1);
        gemmN_kernel<2><<<dim3(1280, 2), 256, 0, stream>>>(z1, cores2, gs1, gq1, g1, b1, M, 0, 1);
        chain_kernel<64, 1280><<<dim3(64, 2), 256, 0, stream>>>(M, label2, z2, gs2, gq2, 0, 1);
        gemmN_kernel<3><<<dim3(320, 2), 256, 0, stream>>>(z2, cores3, gs2, gq2, g2, b2, M, 0, 1);
        chain_kernel<16, 320><<<dim3(16, 2), 256, 0, stream>>>(M, label3, z3, gs3, gq3, 0, 1);
    } else {
        // batch-half passes reusing the M region (mmask = 0)
        for (int bh = 0; bh < 2; ++bh) {
            gemm1_kernel<<<dim3(5120, 1), 256, 0, stream>>>(xT, cores1, M, bh, 0);
            chain_kernel<256, 5120><<<dim3(256, 1), 256, 0, stream>>>(M, label1, z1, gs1, gq1, bh * 64, 0);
        }
        for (int bh = 0; bh < 2; ++bh) {
            gemmN_kernel<2><<<dim3(1280, 1), 256, 0, stream>>>(z1, cores2, gs1, gq1, g1, b1, M, bh, 0);
            chain_kernel<64, 1280><<<dim3(64, 1), 256, 0, stream>>>(M, label2, z2, gs2, gq2, bh * 64, 0);
        }
        for (int bh = 0; bh < 2; ++bh) {
            gemmN_kernel<3><<<dim3(320, 1), 256, 0, stream>>>(z2, cores3, gs2, gq2, g2, b2, M, bh, 0);
            chain_kernel<16, 320><<<dim3(16, 1), 256, 0, stream>>>(M, label3, z3, gs3, gq3, bh * 64, 0);
        }
    }
    final_kernel<<<128, 512, 0, stream>>>(z3, coresF, labelF, g3, b3,
                                          gs3, gq3, (float*)d_out);
}

// Round 7
// 164.811 us; speedup vs baseline: 2.4840x; 1.6885x over previous
//
#include <hip/hip_runtime.h>

#define VB 0.22360679774997896f  // 20^-0.5

typedef __attribute__((ext_vector_type(8))) _Float16 half8;
typedef __attribute__((ext_vector_type(4))) float f32x4;

// workspace float offsets
#define Z1_OFF   0
#define Z2_OFF   655360
#define Z3_OFF   819200
#define GS1_OFF  860160
#define GQ1_OFF  860416
#define GS2_OFF  860672
#define GQ2_OFF  860736
#define GS3_OFF  860800
#define GQ3_OFF  860816
#define LV1_OFF  860832    // 256*400
#define LV2_OFF  963232    // 64*400
#define LV3_OFF  988832    // 16*400
#define XT_OFF   995232    // 1024*6144 = 6291456 floats  (R6 bug: had half this)
#define WH1_OFF  7286688   // 39321600 halfs = 19660800 floats
#define WH2_OFF  26947488  // 6553600 halfs  = 3276800 floats
#define WH3_OFF  30224288  // 1638400 halfs  = 819200 floats ; end 31043488 fl = 124.2 MB

#define WAVEBAR() __builtin_amdgcn_wave_barrier()

// ---------------------------------------------------------------------------
// x transpose: x[b][c][pix] -> xT[pix][b*48+c]  (verified R5)
// ---------------------------------------------------------------------------
__global__ __launch_bounds__(256, 4)
void xt_kernel(const float* __restrict__ x, float* __restrict__ xT)
{
    __shared__ float tS[32 * 193];
    const int tid  = threadIdx.x;
    const int pix0 = (blockIdx.x & 31) * 32;
    const int bc0  = (blockIdx.x >> 5) * 192;
    #pragma unroll
    for (int k = 0; k < 6; ++k) {
        int i = tid + k * 256;
        int r = i >> 3, q = i & 7;
        float4 v = *(const float4*)(x + (size_t)(bc0 + r) * 1024 + pix0 + q * 4);
        tS[(q * 4 + 0) * 193 + r] = v.x;
        tS[(q * 4 + 1) * 193 + r] = v.y;
        tS[(q * 4 + 2) * 193 + r] = v.z;
        tS[(q * 4 + 3) * 193 + r] = v.w;
    }
    __syncthreads();
    #pragma unroll
    for (int k = 0; k < 6; ++k) {
        int o = tid + k * 256;
        int pp = o / 48, c4 = o - pp * 48;
        float4 v;
        v.x = tS[pp * 193 + c4 * 4 + 0];
        v.y = tS[pp * 193 + c4 * 4 + 1];
        v.z = tS[pp * 193 + c4 * 4 + 2];
        v.w = tS[pp * 193 + c4 * 4 + 3];
        *(float4*)(xT + (size_t)(pix0 + pp) * 6144 + bc0 + c4 * 4) = v;
    }
}

// ---------------------------------------------------------------------------
// W conversion stage 1: cores1 fp32 -> fp16 B-frag layout. 5120 chunk-blocks.
// ---------------------------------------------------------------------------
__global__ __launch_bounds__(256, 4)
void wconv1_kernel(const float* __restrict__ cores1, _Float16* __restrict__ Wh)
{
    __shared__ __align__(16) _Float16 fragS[7680];
    const int tid = threadIdx.x;
    const size_t slab = blockIdx.x;
    const float* src = cores1 + slab * 7680;
    #pragma unroll
    for (int k = 0; k < 8; ++k) {
        int i4 = tid + k * 256;
        if (i4 < 1920) {
            float4 w = *(const float4*)(src + i4 * 4);
            float vals[4] = {w.x, w.y, w.z, w.w};
            #pragma unroll
            for (int t = 0; t < 4; ++t) {
                int e = i4 * 4 + t;
                int v = e % 20;
                int r = e / 20;
                int f = r % 96;
                int ul = r / 96;
                int c = ul * 20 + v;
                int addr = (((f >> 5) * 5 + (c >> 4)) * 64 +
                            ((f >> 3) & 3) * 16 + (c & 15)) * 8 + (f & 7);
                fragS[addr] = (_Float16)vals[t];
            }
        }
    }
    __syncthreads();
    uint4* dst = (uint4*)(Wh + slab * 7680);
    #pragma unroll
    for (int k = 0; k < 4; ++k) {
        int i = tid + k * 256;
        if (i < 960) dst[i] = ((const uint4*)fragS)[i];
    }
}

// ---------------------------------------------------------------------------
// W conversion stages 2+3 (F=40, K padded to 64 with zeros). 1600 blocks.
// ---------------------------------------------------------------------------
__global__ __launch_bounds__(256, 4)
void wconv23_kernel(const float* __restrict__ c2, const float* __restrict__ c3,
                    _Float16* __restrict__ Wh2, _Float16* __restrict__ Wh3)
{
    __shared__ __align__(16) _Float16 fragS[5120];
    const int tid = threadIdx.x;
    const int b   = blockIdx.x;
    const float* src;
    _Float16* dst;
    if (b < 1280) { src = c2 + (size_t)b * 3200;          dst = Wh2 + (size_t)b * 5120; }
    else          { src = c3 + (size_t)(b - 1280) * 3200; dst = Wh3 + (size_t)(b - 1280) * 5120; }
    #pragma unroll
    for (int k = 0; k < 3; ++k) {
        int i = tid + k * 256;
        if (i < 640) ((uint4*)fragS)[i] = (uint4){0, 0, 0, 0};
    }
    __syncthreads();
    #pragma unroll
    for (int k = 0; k < 4; ++k) {
        int i4 = tid + k * 256;
        if (i4 < 800) {
            float4 w = *(const float4*)(src + i4 * 4);
            float vals[4] = {w.x, w.y, w.z, w.w};
            #pragma unroll
            for (int t = 0; t < 4; ++t) {
                int e = i4 * 4 + t;
                int v = e % 20;
                int r = e / 20;
                int f = r % 40;
                int ul = r / 40;
                int c = ul * 20 + v;
                int addr = (((f >> 5) * 5 + (c >> 4)) * 64 +
                            ((f >> 3) & 3) * 16 + (c & 15)) * 8 + (f & 7);
                fragS[addr] = (_Float16)vals[t];
            }
        }
    }
    __syncthreads();
    #pragma unroll
    for (int k = 0; k < 3; ++k) {
        int i = tid + k * 256;
        if (i < 640) ((uint4*)dst)[i] = ((const uint4*)fragS)[i];
    }
}

// ---------------------------------------------------------------------------
// Label pre-contraction: labv[p][u][o] = VB * sum_v label[p][u][o][v].
// ---------------------------------------------------------------------------
__global__ __launch_bounds__(256, 4)
void lab_kernel(const float* __restrict__ l1, const float* __restrict__ l2,
                const float* __restrict__ l3,
                float* __restrict__ v1, float* __restrict__ v2, float* __restrict__ v3)
{
    const int b = blockIdx.x, tid = threadIdx.x;
    const float* lb;
    float* ov;
    if (b < 256)      { lb = l1 + (size_t)b * 8000;         ov = v1 + b * 400; }
    else if (b < 320) { lb = l2 + (size_t)(b - 256) * 8000; ov = v2 + (b - 256) * 400; }
    else              { lb = l3 + (size_t)(b - 320) * 8000; ov = v3 + (b - 320) * 400; }
    for (int i = tid; i < 400; i += 256) {
        const float* s = lb + i * 20;
        float acc = 0.f;
        #pragma unroll
        for (int vv = 0; vv < 20; ++vv) acc += s[vv];
        ov[i] = acc * VB;
    }
}

// ---------------------------------------------------------------------------
// Fused stage 1: grid (256 p, 2 bh) x 256 thr. Zero block barriers; each wave
// privately owns 16 batch rows (wave-synchronous LDS). B-frags direct
// global->reg from pre-converted Wh1, double-buffered across u-chunks.
// ---------------------------------------------------------------------------
#define UCBODY1(ucv, CUR, NXT)                                                   \
    {                                                                            \
        if ((ucv) < 4) {                                                         \
            const _Float16* bptr = whp + (size_t)((ucv) + 1) * 7680;             \
            _Pragma("unroll")                                                    \
            for (int q = 0; q < 15; ++q)                                         \
                NXT[q] = *(const half8*)(bptr + (q * 64 + l) * 8);               \
        }                                                                        \
        f32x4 acc[5];                                                            \
        _Pragma("unroll")                                                        \
        for (int nt = 0; nt < 5; ++nt) acc[nt] = (f32x4){0.f, 0.f, 0.f, 0.f};    \
        _Pragma("unroll")                                                        \
        for (int ks = 0; ks < 3; ++ks) {                                         \
            _Pragma("unroll")                                                    \
            for (int nt = 0; nt < 5; ++nt)                                       \
                acc[nt] = __builtin_amdgcn_mfma_f32_16x16x32_f16(                \
                    af[ks], CUR[ks * 5 + nt], acc[nt], 0, 0, 0);                 \
        }                                                                        \
        _Pragma("unroll")                                                        \
        for (int nt = 0; nt < 5; ++nt) {                                         \
            _Pragma("unroll")                                                    \
            for (int r = 0; r < 4; ++r)                                          \
                Mw[(hi * 4 + r) * 84 + nt * 16 + row16] = acc[nt][r];            \
        }                                                                        \
        WAVEBAR();                                                               \
        _Pragma("unroll")                                                        \
        for (int ul = 0; ul < 4; ++ul) {                                         \
            float lvx = lw[bQ * 20 + (ucv) * 4 + ul];                            \
            _Pragma("unroll")                                                    \
            for (int j = 0; j < 5; ++j)                                          \
                lacc[j] += lvx * Mw[bQ * 84 + ul * 20 + mh * 5 + j];             \
        }                                                                        \
        WAVEBAR();                                                               \
    }

__global__ __launch_bounds__(256, 2)
void fused1_kernel(const float* __restrict__ xT, const _Float16* __restrict__ Wh,
                   const float* __restrict__ labv,
                   float* __restrict__ z1, float* __restrict__ gs, float* __restrict__ gq)
{
    __shared__ __align__(16) float xS[4 * 768];
    __shared__ __align__(16) float MchunkS[4 * 16 * 84];
    __shared__ __align__(16) float leftS[4 * 320];

    const int tid = threadIdx.x;
    const int p   = blockIdx.x;
    const int bh  = blockIdx.y;
    const int wv  = tid >> 6, l = tid & 63;
    float* xSw = xS + wv * 768;
    float* Mw  = MchunkS + wv * 1344;
    float* lw  = leftS + wv * 320;
    const int row16 = l & 15, hi = l >> 4;
    const int bQ = l >> 2,   mh = l & 3;
    const int hh  = (p >> 7) * 16 + ((p >> 2) & 15);
    const int ww0 = ((p >> 6) & 1) * 16 + (p & 3) * 4;

    #pragma unroll
    for (int j = 0; j < 5; ++j) lw[bQ * 20 + mh * 5 + j] = VB;
    WAVEBAR();

    float lacc[5] = {0.f, 0.f, 0.f, 0.f, 0.f};

    #pragma unroll 1
    for (int n = 0; n < 4; ++n) {
        // x slab -> wave-private LDS
        const float* xsl = xT + (size_t)(hh * 32 + ww0 + n) * 6144 + bh * 3072 + wv * 768;
        #pragma unroll
        for (int k = 0; k < 3; ++k) {
            float4 v = *(const float4*)(xsl + (l + k * 64) * 4);
            *(float4*)&xSw[(l + k * 64) * 4] = v;
        }
        WAVEBAR();
        // A-frags in registers
        half8 af[3];
        #pragma unroll
        for (int ks = 0; ks < 3; ++ks) {
            int f0 = ks * 32 + hi * 8;
            int cc = (f0 < 48) ? f0 : f0 - 48;
            float4 a  = *(const float4*)&xSw[row16 * 48 + cc];
            float4 b2 = *(const float4*)&xSw[row16 * 48 + cc + 4];
            float vv[8] = {a.x, a.y, a.z, a.w, b2.x, b2.y, b2.z, b2.w};
            bool inv = (f0 >= 48);
            half8 hv;
            #pragma unroll
            for (int j = 0; j < 8; ++j) hv[j] = (_Float16)(inv ? (1.f - vv[j]) : vv[j]);
            af[ks] = hv;
        }
        WAVEBAR();

        const _Float16* whp = Wh + (size_t)((p * 4 + n) * 5) * 7680;
        half8 bA[15], bB[15];
        {
            #pragma unroll
            for (int q = 0; q < 15; ++q) bA[q] = *(const half8*)(whp + (q * 64 + l) * 8);
        }
        UCBODY1(0, bA, bB)
        UCBODY1(1, bB, bA)
        UCBODY1(2, bA, bB)
        UCBODY1(3, bB, bA)
        UCBODY1(4, bA, bB)

        #pragma unroll
        for (int j = 0; j < 5; ++j) { lw[bQ * 20 + mh * 5 + j] = lacc[j]; lacc[j] = 0.f; }
        WAVEBAR();
    }

    // epilogue: labv matvec + z1 + BN sums
    const float* lvp = labv + p * 400;
    #pragma unroll
    for (int k = 0; k < 7; ++k) { int i = l + k * 64; if (i < 400) Mw[i] = lvp[i]; }
    WAVEBAR();
    float yv[5] = {0.f, 0.f, 0.f, 0.f, 0.f};
    #pragma unroll
    for (int u = 0; u < 20; ++u) {
        float lu = lw[bQ * 20 + u];
        #pragma unroll
        for (int j = 0; j < 5; ++j) yv[j] += lu * Mw[u * 20 + mh * 5 + j];
    }
    float s = 0.f, s2 = 0.f;
    #pragma unroll
    for (int j = 0; j < 5; ++j) {
        z1[(size_t)(bh * 64 + wv * 16 + bQ) * 5120 + p * 20 + mh * 5 + j] = yv[j];
        s += yv[j]; s2 += yv[j] * yv[j];
    }
    #pragma unroll
    for (int off = 32; off > 0; off >>= 1) {
        s  += __shfl_down(s, off);
        s2 += __shfl_down(s2, off);
    }
    if (l == 0) { atomicAdd(&gs[p], s); atomicAdd(&gq[p], s2); }
}

// ---------------------------------------------------------------------------
// Fused stages 2 & 3: same skeleton, feat = BN(z_prev), K=64 (2 ks), 10 frags.
// ---------------------------------------------------------------------------
#define UCBODYN(ucv, CUR, NXT)                                                   \
    {                                                                            \
        if ((ucv) < 4) {                                                         \
            const _Float16* bptr = whp + (size_t)((ucv) + 1) * 5120;             \
            _Pragma("unroll")                                                    \
            for (int q = 0; q < 10; ++q)                                         \
                NXT[q] = *(const half8*)(bptr + (q * 64 + l) * 8);               \
        }                                                                        \
        f32x4 acc[5];                                                            \
        _Pragma("unroll")                                                        \
        for (int nt = 0; nt < 5; ++nt) acc[nt] = (f32x4){0.f, 0.f, 0.f, 0.f};    \
        _Pragma("unroll")                                                        \
        for (int ks = 0; ks < 2; ++ks) {                                         \
            _Pragma("unroll")                                                    \
            for (int nt = 0; nt < 5; ++nt)                                       \
                acc[nt] = __builtin_amdgcn_mfma_f32_16x16x32_f16(                \
                    af[ks], CUR[ks * 5 + nt], acc[nt], 0, 0, 0);                 \
        }                                                                        \
        _Pragma("unroll")                                                        \
        for (int nt = 0; nt < 5; ++nt) {                                         \
            _Pragma("unroll")                                                    \
            for (int r = 0; r < 4; ++r)                                          \
                Mw[(hi * 4 + r) * 84 + nt * 16 + row16] = acc[nt][r];            \
        }                                                                        \
        WAVEBAR();                                                               \
        _Pragma("unroll")                                                        \
        for (int ul = 0; ul < 4; ++ul) {                                         \
            float lvx = lw[bQ * 20 + (ucv) * 4 + ul];                            \
            _Pragma("unroll")                                                    \
            for (int j = 0; j < 5; ++j)                                          \
                lacc[j] += lvx * Mw[bQ * 84 + ul * 20 + mh * 5 + j];             \
        }                                                                        \
        WAVEBAR();                                                               \
    }

template <int STAGE>
__global__ __launch_bounds__(256, 2)
void fusedN_kernel(const float* __restrict__ zin, const _Float16* __restrict__ Wh,
                   const float* __restrict__ labv,
                   const float* __restrict__ gsin, const float* __restrict__ gqin,
                   const float* __restrict__ gam,  const float* __restrict__ bet,
                   float* __restrict__ zout,
                   float* __restrict__ gsout, float* __restrict__ gqout)
{
    constexpr int ZIN  = (STAGE == 2) ? 5120 : 1280;
    constexpr int ZOUT = (STAGE == 2) ? 1280 : 320;
    constexpr int JUMP = (STAGE == 2) ? 256 : 64;

    __shared__ __align__(16) float zS[4 * 320];
    __shared__ float scS[4 * 20], shS[4 * 20];
    __shared__ __align__(16) float MchunkS[4 * 16 * 84];
    __shared__ __align__(16) float leftS[4 * 320];

    const int tid = threadIdx.x;
    const int p   = blockIdx.x;
    const int bh  = blockIdx.y;
    const int wv  = tid >> 6, l = tid & 63;
    float* zSw = zS + wv * 320;
    float* scw = scS + wv * 20;
    float* shw = shS + wv * 20;
    float* Mw  = MchunkS + wv * 1344;
    float* lw  = leftS + wv * 320;
    const int row16 = l & 15, hi = l >> 4;
    const int bQ = l >> 2,   mh = l & 3;
    const int bg = bh * 64;

    #pragma unroll
    for (int j = 0; j < 5; ++j) lw[bQ * 20 + mh * 5 + j] = VB;
    WAVEBAR();

    float lacc[5] = {0.f, 0.f, 0.f, 0.f, 0.f};

    #pragma unroll 1
    for (int n = 0; n < 4; ++n) {
        int hh, ww;
        if (STAGE == 2) { hh = (p >> 5) * 8 + ((p >> 1) & 7); ww = ((p >> 4) & 1) * 8 + (p & 1) * 4 + n; }
        else            { hh = (p >> 3) * 4 + (p & 3);        ww = ((p >> 2) & 1) * 4 + n; }
        const int oo = (STAGE == 2) ? (hh * 16 + ww) : (hh * 8 + ww);

        if (l < 20) {
            int ch = (l * JUMP + oo) / 20;
            float mean = gsin[ch] * (1.f / 2560.f);
            float var  = gqin[ch] * (1.f / 2560.f) - mean * mean;
            float rstd = rsqrtf(var + 1e-5f);
            float sc = gam[ch] * rstd;
            scw[l] = sc;
            shw[l] = bet[ch] - mean * sc;
        }
        WAVEBAR();
        #pragma unroll
        for (int q = 0; q < 5; ++q) {
            int d = hi * 5 + q;
            float zraw = zin[(size_t)(bg + wv * 16 + row16) * ZIN + d * JUMP + oo];
            zSw[row16 * 20 + d] = zraw * scw[d] + shw[d];
        }
        WAVEBAR();
        half8 af[2];
        #pragma unroll
        for (int ks = 0; ks < 2; ++ks) {
            int f0 = ks * 32 + hi * 8;
            half8 hv;
            #pragma unroll
            for (int j = 0; j < 8; ++j) {
                int f = f0 + j;
                float val;
                if (f < 20)      val = zSw[row16 * 20 + f];
                else if (f < 40) val = 1.f - zSw[row16 * 20 + f - 20];
                else             val = 0.f;
                hv[j] = (_Float16)val;
            }
            af[ks] = hv;
        }
        WAVEBAR();

        const _Float16* whp = Wh + (size_t)((p * 4 + n) * 5) * 5120;
        half8 bA[10], bB[10];
        {
            #pragma unroll
            for (int q = 0; q < 10; ++q) bA[q] = *(const half8*)(whp + (q * 64 + l) * 8);
        }
        UCBODYN(0, bA, bB)
        UCBODYN(1, bB, bA)
        UCBODYN(2, bA, bB)
        UCBODYN(3, bB, bA)
        UCBODYN(4, bA, bB)

        #pragma unroll
        for (int j = 0; j < 5; ++j) { lw[bQ * 20 + mh * 5 + j] = lacc[j]; lacc[j] = 0.f; }
        WAVEBAR();
    }

    const float* lvp = labv + p * 400;
    #pragma unroll
    for (int k = 0; k < 7; ++k) { int i = l + k * 64; if (i < 400) Mw[i] = lvp[i]; }
    WAVEBAR();
    float yv[5] = {0.f, 0.f, 0.f, 0.f, 0.f};
    #pragma unroll
    for (int u = 0; u < 20; ++u) {
        float lu = lw[bQ * 20 + u];
        #pragma unroll
        for (int j = 0; j < 5; ++j) yv[j] += lu * Mw[u * 20 + mh * 5 + j];
    }
    float s = 0.f, s2 = 0.f;
    #pragma unroll
    for (int j = 0; j < 5; ++j) {
        zout[(size_t)(bg + wv * 16 + bQ) * ZOUT + p * 20 + mh * 5 + j] = yv[j];
        s += yv[j]; s2 += yv[j] * yv[j];
    }
    #pragma unroll
    for (int off = 32; off > 0; off >>= 1) {
        s  += __shfl_down(s, off);
        s2 += __shfl_down(s2, off);
    }
    if (l == 0) { atomicAdd(&gsout[p], s); atomicAdd(&gqout[p], s2); }
}

// ---------------------------------------------------------------------------
// Final MPS (unchanged, verified)
// ---------------------------------------------------------------------------
__global__ __launch_bounds__(512, 2)
void final_kernel(const float* __restrict__ z3,
                  const float* __restrict__ coresF,
                  const float* __restrict__ labelF,
                  const float* __restrict__ g3,
                  const float* __restrict__ b3,
                  const float* __restrict__ gsum3,
                  const float* __restrict__ gsq3,
                  float* __restrict__ out)
{
    __shared__ float fS[40];
    __shared__ float mS[400];
    __shared__ float leftS[20];
    __shared__ float lvS[200];
    __shared__ float scS[16], shS[16];

    const int b   = blockIdx.x;
    const int tid = threadIdx.x;

    if (tid < 16) {
        float mean = gsum3[tid] * (1.f / 2560.f);
        float var  = gsq3[tid] * (1.f / 2560.f) - mean * mean;
        float rstd = rsqrtf(var + 1e-5f);
        float sc   = g3[tid] * rstd;
        scS[tid] = sc;
        shS[tid] = b3[tid] - mean * sc;
    }
    if (tid < 20) leftS[tid] = VB;
    __syncthreads();

    #pragma unroll 1
    for (int n = 0; n < 16; ++n) {
        if (tid < 20) {
            float raw = z3[(size_t)b * 320 + n * 20 + tid];
            float val = raw * scS[n] + shS[n];
            fS[tid]      = val;
            fS[20 + tid] = 1.f - val;
        }
        __syncthreads();
        if (tid < 400) {
            int u  = tid / 20;
            int vv = tid - u * 20;
            const float* wb = coresF + ((size_t)(n * 20 + u) * 40) * 20 + vv;
            float acc = 0.f;
            #pragma unroll
            for (int f = 0; f < 40; ++f) acc += fS[f] * wb[f * 20];
            mS[tid] = acc;
        }
        __syncthreads();
        float tmp = 0.f;
        if (tid < 20) {
            #pragma unroll
            for (int u = 0; u < 20; ++u) tmp += leftS[u] * mS[u * 20 + tid];
        }
        __syncthreads();
        if (tid < 20) leftS[tid] = tmp;
        __syncthreads();
    }
    if (tid < 200) {
        int u = tid / 10;
        int o = tid - u * 10;
        const float* lb = labelF + (size_t)(u * 10 + o) * 20;
        float s = 0.f;
        #pragma unroll
        for (int vv = 0; vv < 20; ++vv) s += lb[vv];
        lvS[tid] = s * VB;
    }
    __syncthreads();
    if (tid < 10) {
        float s = 0.f;
        #pragma unroll
        for (int u = 0; u < 20; ++u) s += leftS[u] * lvS[u * 10 + tid];
        out[b * 10 + tid] = s;
    }
}

// ---------------------------------------------------------------------------
extern "C" void kernel_launch(void* const* d_in, const int* in_sizes, int n_in,
                              void* d_out, int out_size, void* d_ws, size_t ws_size,
                              hipStream_t stream)
{
    const float* x      = (const float*)d_in[0];
    const float* cores1 = (const float*)d_in[1];
    const float* label1 = (const float*)d_in[2];
    const float* g1     = (const float*)d_in[3];
    const float* b1     = (const float*)d_in[4];
    const float* cores2 = (const float*)d_in[5];
    const float* label2 = (const float*)d_in[6];
    const float* g2     = (const float*)d_in[7];
    const float* b2     = (const float*)d_in[8];
    const float* cores3 = (const float*)d_in[9];
    const float* label3 = (const float*)d_in[10];
    const float* g3     = (const float*)d_in[11];
    const float* b3     = (const float*)d_in[12];
    const float* coresF = (const float*)d_in[13];
    const float* labelF = (const float*)d_in[14];

    float* ws  = (float*)d_ws;
    float* z1  = ws + Z1_OFF;
    float* z2  = ws + Z2_OFF;
    float* z3  = ws + Z3_OFF;
    float* gs1 = ws + GS1_OFF; float* gq1 = ws + GQ1_OFF;
    float* gs2 = ws + GS2_OFF; float* gq2 = ws + GQ2_OFF;
    float* gs3 = ws + GS3_OFF; float* gq3 = ws + GQ3_OFF;
    float* lv1 = ws + LV1_OFF;
    float* lv2 = ws + LV2_OFF;
    float* lv3 = ws + LV3_OFF;
    float* xT  = ws + XT_OFF;
    _Float16* Wh1 = (_Float16*)(ws + WH1_OFF);
    _Float16* Wh2 = (_Float16*)(ws + WH2_OFF);
    _Float16* Wh3 = (_Float16*)(ws + WH3_OFF);

    hipMemsetAsync(gs1, 0, 672 * sizeof(float), stream);
    xt_kernel<<<1024, 256, 0, stream>>>(x, xT);
    wconv1_kernel<<<5120, 256, 0, stream>>>(cores1, Wh1);
    wconv23_kernel<<<1600, 256, 0, stream>>>(cores2, cores3, Wh2, Wh3);
    lab_kernel<<<336, 256, 0, stream>>>(label1, label2, label3, lv1, lv2, lv3);

    fused1_kernel<<<dim3(256, 2), 256, 0, stream>>>(xT, Wh1, lv1, z1, gs1, gq1);
    fusedN_kernel<2><<<dim3(64, 2), 256, 0, stream>>>(z1, Wh2, lv2, gs1, gq1, g1, b1,
                                                      z2, gs2, gq2);
    fusedN_kernel<3><<<dim3(16, 2), 256, 0, stream>>>(z2, Wh3, lv3, gs2, gq2, g2, b2,
                                                      z3, gs3, gq3);
    final_kernel<<<128, 512, 0, stream>>>(z3, coresF, labelF, g3, b3,
                                          gs3, gq3, (float*)d_out);
}

// Round 8
// 149.648 us; speedup vs baseline: 2.7357x; 1.1013x over previous
//
#include <hip/hip_runtime.h>

#define VB 0.22360679774997896f  // 20^-0.5

typedef __attribute__((ext_vector_type(8))) _Float16 half8;
typedef __attribute__((ext_vector_type(4))) float f32x4;

// workspace float offsets
#define Z1_OFF   0
#define Z2_OFF   655360
#define Z3_OFF   819200
#define GS1_OFF  860160
#define GQ1_OFF  860416
#define GS2_OFF  860672
#define GQ2_OFF  860736
#define GS3_OFF  860800
#define GQ3_OFF  860816
#define LV1_OFF  860832    // 256*400
#define LV2_OFF  963232    // 64*400
#define LV3_OFF  988832    // 16*400
#define XT_OFF   995232    // 1024*6144 = 6291456 floats
#define WH1_OFF  7286688   // 39321600 halfs = 19660800 floats
#define WH2_OFF  26947488  // 6553600 halfs  = 3276800 floats
#define WH3_OFF  30224288  // 1638400 halfs  = 819200 floats ; end 31043488 fl

#define WAVEBAR() __builtin_amdgcn_wave_barrier()

// ---------------------------------------------------------------------------
// Merged prep: one launch, 8081 blocks x 256 thr.
//   [0,1024)      : x transpose  x[b][c][pix] -> xT[pix][b*48+c]
//   [1024,6144)   : cores1 fp32 -> fp16 B-frag layout (slab = b-1024)
//   [6144,7744)   : cores2/3 -> fp16 B-frag layout (K padded to 64)
//   [7744,8080)   : label pre-contraction labv = VB * sum_v label
//   8080          : zero BN atomic-sum region (672 floats)
// ---------------------------------------------------------------------------
__global__ __launch_bounds__(256, 4)
void prep_kernel(const float* __restrict__ x,
                 const float* __restrict__ cores1,
                 const float* __restrict__ c2, const float* __restrict__ c3,
                 const float* __restrict__ l1, const float* __restrict__ l2,
                 const float* __restrict__ l3,
                 float* __restrict__ xT,
                 _Float16* __restrict__ Wh1, _Float16* __restrict__ Wh2,
                 _Float16* __restrict__ Wh3,
                 float* __restrict__ v1, float* __restrict__ v2,
                 float* __restrict__ v3,
                 float* __restrict__ gzero)
{
    __shared__ __align__(16) char ldsU[24704];
    const int tid = threadIdx.x;
    const int b   = blockIdx.x;

    if (b < 1024) {
        // ---- x transpose ----
        float* tS = (float*)ldsU;                  // [32*193]
        const int pix0 = (b & 31) * 32;
        const int bc0  = (b >> 5) * 192;
        #pragma unroll
        for (int k = 0; k < 6; ++k) {
            int i = tid + k * 256;
            int r = i >> 3, q = i & 7;
            float4 v = *(const float4*)(x + (size_t)(bc0 + r) * 1024 + pix0 + q * 4);
            tS[(q * 4 + 0) * 193 + r] = v.x;
            tS[(q * 4 + 1) * 193 + r] = v.y;
            tS[(q * 4 + 2) * 193 + r] = v.z;
            tS[(q * 4 + 3) * 193 + r] = v.w;
        }
        __syncthreads();
        #pragma unroll
        for (int k = 0; k < 6; ++k) {
            int o = tid + k * 256;
            int pp = o / 48, c4 = o - pp * 48;
            float4 v;
            v.x = tS[pp * 193 + c4 * 4 + 0];
            v.y = tS[pp * 193 + c4 * 4 + 1];
            v.z = tS[pp * 193 + c4 * 4 + 2];
            v.w = tS[pp * 193 + c4 * 4 + 3];
            *(float4*)(xT + (size_t)(pix0 + pp) * 6144 + bc0 + c4 * 4) = v;
        }
    } else if (b < 6144) {
        // ---- wconv1 ----
        _Float16* fragS = (_Float16*)ldsU;         // [7680]
        const size_t slab = b - 1024;
        const float* src = cores1 + slab * 7680;
        #pragma unroll
        for (int k = 0; k < 8; ++k) {
            int i4 = tid + k * 256;
            if (i4 < 1920) {
                float4 w = *(const float4*)(src + i4 * 4);
                float vals[4] = {w.x, w.y, w.z, w.w};
                #pragma unroll
                for (int t = 0; t < 4; ++t) {
                    int e = i4 * 4 + t;
                    int v = e % 20;
                    int r = e / 20;
                    int f = r % 96;
                    int ul = r / 96;
                    int c = ul * 20 + v;
                    int addr = (((f >> 5) * 5 + (c >> 4)) * 64 +
                                ((f >> 3) & 3) * 16 + (c & 15)) * 8 + (f & 7);
                    fragS[addr] = (_Float16)vals[t];
                }
            }
        }
        __syncthreads();
        uint4* dst = (uint4*)(Wh1 + slab * 7680);
        #pragma unroll
        for (int k = 0; k < 4; ++k) {
            int i = tid + k * 256;
            if (i < 960) dst[i] = ((const uint4*)fragS)[i];
        }
    } else if (b < 7744) {
        // ---- wconv2/3 ----
        _Float16* fragS = (_Float16*)ldsU;         // [5120]
        const int bb = b - 6144;
        const float* src;
        _Float16* dst;
        if (bb < 1280) { src = c2 + (size_t)bb * 3200;          dst = Wh2 + (size_t)bb * 5120; }
        else           { src = c3 + (size_t)(bb - 1280) * 3200; dst = Wh3 + (size_t)(bb - 1280) * 5120; }
        #pragma unroll
        for (int k = 0; k < 3; ++k) {
            int i = tid + k * 256;
            if (i < 640) ((uint4*)fragS)[i] = (uint4){0, 0, 0, 0};
        }
        __syncthreads();
        #pragma unroll
        for (int k = 0; k < 4; ++k) {
            int i4 = tid + k * 256;
            if (i4 < 800) {
                float4 w = *(const float4*)(src + i4 * 4);
                float vals[4] = {w.x, w.y, w.z, w.w};
                #pragma unroll
                for (int t = 0; t < 4; ++t) {
                    int e = i4 * 4 + t;
                    int v = e % 20;
                    int r = e / 20;
                    int f = r % 40;
                    int ul = r / 40;
                    int c = ul * 20 + v;
                    int addr = (((f >> 5) * 5 + (c >> 4)) * 64 +
                                ((f >> 3) & 3) * 16 + (c & 15)) * 8 + (f & 7);
                    fragS[addr] = (_Float16)vals[t];
                }
            }
        }
        __syncthreads();
        #pragma unroll
        for (int k = 0; k < 3; ++k) {
            int i = tid + k * 256;
            if (i < 640) ((uint4*)dst)[i] = ((const uint4*)fragS)[i];
        }
    } else if (b < 8080) {
        // ---- label pre-contraction ----
        const int bb = b - 7744;
        const float* lb;
        float* ov;
        if (bb < 256)      { lb = l1 + (size_t)bb * 8000;         ov = v1 + bb * 400; }
        else if (bb < 320) { lb = l2 + (size_t)(bb - 256) * 8000; ov = v2 + (bb - 256) * 400; }
        else               { lb = l3 + (size_t)(bb - 320) * 8000; ov = v3 + (bb - 320) * 400; }
        for (int i = tid; i < 400; i += 256) {
            const float* s = lb + i * 20;
            float acc = 0.f;
            #pragma unroll
            for (int vv = 0; vv < 20; ++vv) acc += s[vv];
            ov[i] = acc * VB;
        }
    } else {
        // ---- zero BN sums ----
        if (tid < 256) {
            for (int i = tid; i < 672; i += 256) gzero[i] = 0.f;
        }
    }
}

// ---------------------------------------------------------------------------
// Fused stage 1 (verified R7): grid (256 p, 2 bh) x 256 thr, zero block
// barriers, wave-private 16 batch rows, B-frags global->reg double-buffered.
// ---------------------------------------------------------------------------
#define UCBODY1(ucv, CUR, NXT)                                                   \
    {                                                                            \
        if ((ucv) < 4) {                                                         \
            const _Float16* bptr = whp + (size_t)((ucv) + 1) * 7680;             \
            _Pragma("unroll")                                                    \
            for (int q = 0; q < 15; ++q)                                         \
                NXT[q] = *(const half8*)(bptr + (q * 64 + l) * 8);               \
        }                                                                        \
        f32x4 acc[5];                                                            \
        _Pragma("unroll")                                                        \
        for (int nt = 0; nt < 5; ++nt) acc[nt] = (f32x4){0.f, 0.f, 0.f, 0.f};    \
        _Pragma("unroll")                                                        \
        for (int ks = 0; ks < 3; ++ks) {                                         \
            _Pragma("unroll")                                                    \
            for (int nt = 0; nt < 5; ++nt)                                       \
                acc[nt] = __builtin_amdgcn_mfma_f32_16x16x32_f16(                \
                    af[ks], CUR[ks * 5 + nt], acc[nt], 0, 0, 0);                 \
        }                                                                        \
        _Pragma("unroll")                                                        \
        for (int nt = 0; nt < 5; ++nt) {                                         \
            _Pragma("unroll")                                                    \
            for (int r = 0; r < 4; ++r)                                          \
                Mw[(hi * 4 + r) * 84 + nt * 16 + row16] = acc[nt][r];            \
        }                                                                        \
        WAVEBAR();                                                               \
        _Pragma("unroll")                                                        \
        for (int ul = 0; ul < 4; ++ul) {                                         \
            float lvx = lw[bQ * 20 + (ucv) * 4 + ul];                            \
            _Pragma("unroll")                                                    \
            for (int j = 0; j < 5; ++j)                                          \
                lacc[j] += lvx * Mw[bQ * 84 + ul * 20 + mh * 5 + j];             \
        }                                                                        \
        WAVEBAR();                                                               \
    }

__global__ __launch_bounds__(256, 2)
void fused1_kernel(const float* __restrict__ xT, const _Float16* __restrict__ Wh,
                   const float* __restrict__ labv,
                   float* __restrict__ z1, float* __restrict__ gs, float* __restrict__ gq)
{
    __shared__ __align__(16) float xS[4 * 768];
    __shared__ __align__(16) float MchunkS[4 * 16 * 84];
    __shared__ __align__(16) float leftS[4 * 320];

    const int tid = threadIdx.x;
    const int p   = blockIdx.x;
    const int bh  = blockIdx.y;
    const int wv  = tid >> 6, l = tid & 63;
    float* xSw = xS + wv * 768;
    float* Mw  = MchunkS + wv * 1344;
    float* lw  = leftS + wv * 320;
    const int row16 = l & 15, hi = l >> 4;
    const int bQ = l >> 2,   mh = l & 3;
    const int hh  = (p >> 7) * 16 + ((p >> 2) & 15);
    const int ww0 = ((p >> 6) & 1) * 16 + (p & 3) * 4;

    #pragma unroll
    for (int j = 0; j < 5; ++j) lw[bQ * 20 + mh * 5 + j] = VB;
    WAVEBAR();

    float lacc[5] = {0.f, 0.f, 0.f, 0.f, 0.f};

    #pragma unroll 1
    for (int n = 0; n < 4; ++n) {
        const float* xsl = xT + (size_t)(hh * 32 + ww0 + n) * 6144 + bh * 3072 + wv * 768;
        #pragma unroll
        for (int k = 0; k < 3; ++k) {
            float4 v = *(const float4*)(xsl + (l + k * 64) * 4);
            *(float4*)&xSw[(l + k * 64) * 4] = v;
        }
        WAVEBAR();
        half8 af[3];
        #pragma unroll
        for (int ks = 0; ks < 3; ++ks) {
            int f0 = ks * 32 + hi * 8;
            int cc = (f0 < 48) ? f0 : f0 - 48;
            float4 a  = *(const float4*)&xSw[row16 * 48 + cc];
            float4 b2 = *(const float4*)&xSw[row16 * 48 + cc + 4];
            float vv[8] = {a.x, a.y, a.z, a.w, b2.x, b2.y, b2.z, b2.w};
            bool inv = (f0 >= 48);
            half8 hv;
            #pragma unroll
            for (int j = 0; j < 8; ++j) hv[j] = (_Float16)(inv ? (1.f - vv[j]) : vv[j]);
            af[ks] = hv;
        }
        WAVEBAR();

        const _Float16* whp = Wh + (size_t)((p * 4 + n) * 5) * 7680;
        half8 bA[15], bB[15];
        {
            #pragma unroll
            for (int q = 0; q < 15; ++q) bA[q] = *(const half8*)(whp + (q * 64 + l) * 8);
        }
        UCBODY1(0, bA, bB)
        UCBODY1(1, bB, bA)
        UCBODY1(2, bA, bB)
        UCBODY1(3, bB, bA)
        UCBODY1(4, bA, bB)

        #pragma unroll
        for (int j = 0; j < 5; ++j) { lw[bQ * 20 + mh * 5 + j] = lacc[j]; lacc[j] = 0.f; }
        WAVEBAR();
    }

    const float* lvp = labv + p * 400;
    #pragma unroll
    for (int k = 0; k < 7; ++k) { int i = l + k * 64; if (i < 400) Mw[i] = lvp[i]; }
    WAVEBAR();
    float yv[5] = {0.f, 0.f, 0.f, 0.f, 0.f};
    #pragma unroll
    for (int u = 0; u < 20; ++u) {
        float lu = lw[bQ * 20 + u];
        #pragma unroll
        for (int j = 0; j < 5; ++j) yv[j] += lu * Mw[u * 20 + mh * 5 + j];
    }
    float s = 0.f, s2 = 0.f;
    #pragma unroll
    for (int j = 0; j < 5; ++j) {
        z1[(size_t)(bh * 64 + wv * 16 + bQ) * 5120 + p * 20 + mh * 5 + j] = yv[j];
        s += yv[j]; s2 += yv[j] * yv[j];
    }
    #pragma unroll
    for (int off = 32; off > 0; off >>= 1) {
        s  += __shfl_down(s, off);
        s2 += __shfl_down(s2, off);
    }
    if (l == 0) { atomicAdd(&gs[p], s); atomicAdd(&gq[p], s2); }
}

// ---------------------------------------------------------------------------
// Fused stages 2 & 3 (verified R7)
// ---------------------------------------------------------------------------
#define UCBODYN(ucv, CUR, NXT)                                                   \
    {                                                                            \
        if ((ucv) < 4) {                                                         \
            const _Float16* bptr = whp + (size_t)((ucv) + 1) * 5120;             \
            _Pragma("unroll")                                                    \
            for (int q = 0; q < 10; ++q)                                         \
                NXT[q] = *(const half8*)(bptr + (q * 64 + l) * 8);               \
        }                                                                        \
        f32x4 acc[5];                                                            \
        _Pragma("unroll")                                                        \
        for (int nt = 0; nt < 5; ++nt) acc[nt] = (f32x4){0.f, 0.f, 0.f, 0.f};    \
        _Pragma("unroll")                                                        \
        for (int ks = 0; ks < 2; ++ks) {                                         \
            _Pragma("unroll")                                                    \
            for (int nt = 0; nt < 5; ++nt)                                       \
                acc[nt] = __builtin_amdgcn_mfma_f32_16x16x32_f16(                \
                    af[ks], CUR[ks * 5 + nt], acc[nt], 0, 0, 0);                 \
        }                                                                        \
        _Pragma("unroll")                                                        \
        for (int nt = 0; nt < 5; ++nt) {                                         \
            _Pragma("unroll")                                                    \
            for (int r = 0; r < 4; ++r)                                          \
                Mw[(hi * 4 + r) * 84 + nt * 16 + row16] = acc[nt][r];            \
        }                                                                        \
        WAVEBAR();                                                               \
        _Pragma("unroll")                                                        \
        for (int ul = 0; ul < 4; ++ul) {                                         \
            float lvx = lw[bQ * 20 + (ucv) * 4 + ul];                            \
            _Pragma("unroll")                                                    \
            for (int j = 0; j < 5; ++j)                                          \
                lacc[j] += lvx * Mw[bQ * 84 + ul * 20 + mh * 5 + j];             \
        }                                                                        \
        WAVEBAR();                                                               \
    }

template <int STAGE>
__global__ __launch_bounds__(256, 2)
void fusedN_kernel(const float* __restrict__ zin, const _Float16* __restrict__ Wh,
                   const float* __restrict__ labv,
                   const float* __restrict__ gsin, const float* __restrict__ gqin,
                   const float* __restrict__ gam,  const float* __restrict__ bet,
                   float* __restrict__ zout,
                   float* __restrict__ gsout, float* __restrict__ gqout)
{
    constexpr int ZIN  = (STAGE == 2) ? 5120 : 1280;
    constexpr int ZOUT = (STAGE == 2) ? 1280 : 320;
    constexpr int JUMP = (STAGE == 2) ? 256 : 64;

    __shared__ __align__(16) float zS[4 * 320];
    __shared__ float scS[4 * 20], shS[4 * 20];
    __shared__ __align__(16) float MchunkS[4 * 16 * 84];
    __shared__ __align__(16) float leftS[4 * 320];

    const int tid = threadIdx.x;
    const int p   = blockIdx.x;
    const int bh  = blockIdx.y;
    const int wv  = tid >> 6, l = tid & 63;
    float* zSw = zS + wv * 320;
    float* scw = scS + wv * 20;
    float* shw = shS + wv * 20;
    float* Mw  = MchunkS + wv * 1344;
    float* lw  = leftS + wv * 320;
    const int row16 = l & 15, hi = l >> 4;
    const int bQ = l >> 2,   mh = l & 3;
    const int bg = bh * 64;

    #pragma unroll
    for (int j = 0; j < 5; ++j) lw[bQ * 20 + mh * 5 + j] = VB;
    WAVEBAR();

    float lacc[5] = {0.f, 0.f, 0.f, 0.f, 0.f};

    #pragma unroll 1
    for (int n = 0; n < 4; ++n) {
        int hh, ww;
        if (STAGE == 2) { hh = (p >> 5) * 8 + ((p >> 1) & 7); ww = ((p >> 4) & 1) * 8 + (p & 1) * 4 + n; }
        else            { hh = (p >> 3) * 4 + (p & 3);        ww = ((p >> 2) & 1) * 4 + n; }
        const int oo = (STAGE == 2) ? (hh * 16 + ww) : (hh * 8 + ww);

        if (l < 20) {
            int ch = (l * JUMP + oo) / 20;
            float mean = gsin[ch] * (1.f / 2560.f);
            float var  = gqin[ch] * (1.f / 2560.f) - mean * mean;
            float rstd = rsqrtf(var + 1e-5f);
            float sc = gam[ch] * rstd;
            scw[l] = sc;
            shw[l] = bet[ch] - mean * sc;
        }
        WAVEBAR();
        #pragma unroll
        for (int q = 0; q < 5; ++q) {
            int d = hi * 5 + q;
            float zraw = zin[(size_t)(bg + wv * 16 + row16) * ZIN + d * JUMP + oo];
            zSw[row16 * 20 + d] = zraw * scw[d] + shw[d];
        }
        WAVEBAR();
        half8 af[2];
        #pragma unroll
        for (int ks = 0; ks < 2; ++ks) {
            int f0 = ks * 32 + hi * 8;
            half8 hv;
            #pragma unroll
            for (int j = 0; j < 8; ++j) {
                int f = f0 + j;
                float val;
                if (f < 20)      val = zSw[row16 * 20 + f];
                else if (f < 40) val = 1.f - zSw[row16 * 20 + f - 20];
                else             val = 0.f;
                hv[j] = (_Float16)val;
            }
            af[ks] = hv;
        }
        WAVEBAR();

        const _Float16* whp = Wh + (size_t)((p * 4 + n) * 5) * 5120;
        half8 bA[10], bB[10];
        {
            #pragma unroll
            for (int q = 0; q < 10; ++q) bA[q] = *(const half8*)(whp + (q * 64 + l) * 8);
        }
        UCBODYN(0, bA, bB)
        UCBODYN(1, bB, bA)
        UCBODYN(2, bA, bB)
        UCBODYN(3, bB, bA)
        UCBODYN(4, bA, bB)

        #pragma unroll
        for (int j = 0; j < 5; ++j) { lw[bQ * 20 + mh * 5 + j] = lacc[j]; lacc[j] = 0.f; }
        WAVEBAR();
    }

    const float* lvp = labv + p * 400;
    #pragma unroll
    for (int k = 0; k < 7; ++k) { int i = l + k * 64; if (i < 400) Mw[i] = lvp[i]; }
    WAVEBAR();
    float yv[5] = {0.f, 0.f, 0.f, 0.f, 0.f};
    #pragma unroll
    for (int u = 0; u < 20; ++u) {
        float lu = lw[bQ * 20 + u];
        #pragma unroll
        for (int j = 0; j < 5; ++j) yv[j] += lu * Mw[u * 20 + mh * 5 + j];
    }
    float s = 0.f, s2 = 0.f;
    #pragma unroll
    for (int j = 0; j < 5; ++j) {
        zout[(size_t)(bg + wv * 16 + bQ) * ZOUT + p * 20 + mh * 5 + j] = yv[j];
        s += yv[j]; s2 += yv[j] * yv[j];
    }
    #pragma unroll
    for (int off = 32; off > 0; off >>= 1) {
        s  += __shfl_down(s, off);
        s2 += __shfl_down(s2, off);
    }
    if (l == 0) { atomicAdd(&gsout[p], s); atomicAdd(&gqout[p], s2); }
}

// ---------------------------------------------------------------------------
// Final MPS, restructured: parallel M build for all 16 sites (2 barriers),
// then single-wave barrier-free chain. 128 blocks x 256 thr.
// ---------------------------------------------------------------------------
__global__ __launch_bounds__(256, 4)
void final_kernel(const float* __restrict__ z3,
                  const float* __restrict__ coresF,
                  const float* __restrict__ labelF,
                  const float* __restrict__ g3,
                  const float* __restrict__ b3,
                  const float* __restrict__ gsum3,
                  const float* __restrict__ gsq3,
                  float* __restrict__ out)
{
    __shared__ __align__(16) float fS[16 * 40];
    __shared__ __align__(16) float MS[16 * 400];
    __shared__ float lvS[200];
    __shared__ float scS[16], shS[16];
    __shared__ float leftS[20];

    const int b   = blockIdx.x;
    const int tid = threadIdx.x;

    if (tid < 16) {
        float mean = gsum3[tid] * (1.f / 2560.f);
        float var  = gsq3[tid] * (1.f / 2560.f) - mean * mean;
        float rstd = rsqrtf(var + 1e-5f);
        float sc   = g3[tid] * rstd;
        scS[tid] = sc;
        shS[tid] = b3[tid] - mean * sc;
    }
    __syncthreads();

    // feat for all 16 sites + labv (independent work, no ordering needed)
    for (int i = tid; i < 640; i += 256) {
        int n = i / 40, f = i - n * 40;
        float raw = z3[(size_t)b * 320 + n * 20 + (f % 20)];
        float val = raw * scS[n] + shS[n];
        fS[i] = (f < 20) ? val : (1.f - val);
    }
    for (int i = tid; i < 200; i += 256) {
        int u = i / 10, o = i - u * 10;
        const float* lb = labelF + (size_t)(u * 10 + o) * 20;
        float s = 0.f;
        #pragma unroll
        for (int vv = 0; vv < 20; ++vv) s += lb[vv];
        lvS[i] = s * VB;
    }
    __syncthreads();

    // M[n][u][v] for all sites in parallel: 6400 dots of length 40
    for (int i = tid; i < 6400; i += 256) {
        int n = i / 400, uv = i - n * 400;
        int u = uv / 20, v = uv - u * 20;
        const float* wb = coresF + ((size_t)(n * 20 + u) * 40) * 20 + v;
        const float* fb = fS + n * 40;
        float acc = 0.f;
        #pragma unroll
        for (int f = 0; f < 40; ++f) acc += fb[f] * wb[f * 20];
        MS[i] = acc;
    }
    __syncthreads();

    // single-wave chain (wave 0, barrier-free)
    if (tid < 64) {
        if (tid < 20) leftS[tid] = VB;
        WAVEBAR();
        #pragma unroll 1
        for (int n = 0; n < 16; ++n) {
            float tmp = 0.f;
            if (tid < 20) {
                #pragma unroll
                for (int u = 0; u < 20; ++u) tmp += leftS[u] * MS[n * 400 + u * 20 + tid];
            }
            WAVEBAR();
            if (tid < 20) leftS[tid] = tmp;
            WAVEBAR();
        }
        if (tid < 10) {
            float s = 0.f;
            #pragma unroll
            for (int u = 0; u < 20; ++u) s += leftS[u] * lvS[u * 10 + tid];
            out[b * 10 + tid] = s;
        }
    }
}

// ---------------------------------------------------------------------------
extern "C" void kernel_launch(void* const* d_in, const int* in_sizes, int n_in,
                              void* d_out, int out_size, void* d_ws, size_t ws_size,
                              hipStream_t stream)
{
    const float* x      = (const float*)d_in[0];
    const float* cores1 = (const float*)d_in[1];
    const float* label1 = (const float*)d_in[2];
    const float* g1     = (const float*)d_in[3];
    const float* b1     = (const float*)d_in[4];
    const float* cores2 = (const float*)d_in[5];
    const float* label2 = (const float*)d_in[6];
    const float* g2     = (const float*)d_in[7];
    const float* b2     = (const float*)d_in[8];
    const float* cores3 = (const float*)d_in[9];
    const float* label3 = (const float*)d_in[10];
    const float* g3     = (const float*)d_in[11];
    const float* b3     = (const float*)d_in[12];
    const float* coresF = (const float*)d_in[13];
    const float* labelF = (const float*)d_in[14];

    float* ws  = (float*)d_ws;
    float* z1  = ws + Z1_OFF;
    float* z2  = ws + Z2_OFF;
    float* z3  = ws + Z3_OFF;
    float* gs1 = ws + GS1_OFF; float* gq1 = ws + GQ1_OFF;
    float* gs2 = ws + GS2_OFF; float* gq2 = ws + GQ2_OFF;
    float* gs3 = ws + GS3_OFF; float* gq3 = ws + GQ3_OFF;
    float* lv1 = ws + LV1_OFF;
    float* lv2 = ws + LV2_OFF;
    float* lv3 = ws + LV3_OFF;
    float* xT  = ws + XT_OFF;
    _Float16* Wh1 = (_Float16*)(ws + WH1_OFF);
    _Float16* Wh2 = (_Float16*)(ws + WH2_OFF);
    _Float16* Wh3 = (_Float16*)(ws + WH3_OFF);

    prep_kernel<<<8081, 256, 0, stream>>>(x, cores1, cores2, cores3,
                                          label1, label2, label3,
                                          xT, Wh1, Wh2, Wh3,
                                          lv1, lv2, lv3, gs1);

    fused1_kernel<<<dim3(256, 2), 256, 0, stream>>>(xT, Wh1, lv1, z1, gs1, gq1);
    fusedN_kernel<2><<<dim3(64, 2), 256, 0, stream>>>(z1, Wh2, lv2, gs1, gq1, g1, b1,
                                                      z2, gs2, gq2);
    fusedN_kernel<3><<<dim3(16, 2), 256, 0, stream>>>(z2, Wh3, lv3, gs2, gq2, g2, b2,
                                                      z3, gs3, gq3);
    final_kernel<<<128, 256, 0, stream>>>(z3, coresF, labelF, g3, b3,
                                          gs3, gq3, (float*)d_out);
}